// Round 9
// baseline (1425.480 us; speedup 1.0000x reference)
//
#include <hip/hip_runtime.h>
#include <cstdint>

#define BT 4096
#define H  2048
#define V  32000
#define TM 128
#define TN 128
#define BK 128          // fp8 bytes == elements per K-tile
#define NT (H/BK)       // 16
#define NRT (BT/TM)     // 32
#define NVT (V/TN)      // 250
#define PJ  256         // padded partials row stride (floats)
#define WSCALE 64.0f
#define INV_WSCALE 0.015625f

typedef int   v8i   __attribute__((ext_vector_type(8)));
typedef float f32x4 __attribute__((ext_vector_type(4)));
typedef float f4v   __attribute__((ext_vector_type(4)));

__device__ __forceinline__ void async_load16(const void* g, void* l) {
    __builtin_amdgcn_global_load_lds(
        (__attribute__((address_space(1))) uint32_t*)(void*)g,
        (__attribute__((address_space(3))) uint32_t*)l, 16, 0, 0);
}

// ------- quantize X and W fp32 -> fp8 e4m3 in ONE kernel, 16B/lane loads ----
__global__ void quant_all(const float* __restrict__ X, const float* __restrict__ W,
                          int* __restrict__ Xq, int* __restrict__ Wq,
                          float* __restrict__ accum) {
    const int NX = BT * H / 4;
    const int NW = (int)((size_t)V * H / 4);
    int i = blockIdx.x * blockDim.x + threadIdx.x;
    if (i == 0) { accum[0] = 0.f; accum[1] = 0.f; }
    if (i < NX) {
        f4v v = __builtin_nontemporal_load((const f4v*)X + i);
        int p = __builtin_amdgcn_cvt_pk_fp8_f32(v.x, v.y, 0, false);
        p     = __builtin_amdgcn_cvt_pk_fp8_f32(v.z, v.w, p, true);
        Xq[i] = p;
    } else if (i < NX + NW) {
        int j = i - NX;
        f4v v = __builtin_nontemporal_load((const f4v*)W + j);
        int p = __builtin_amdgcn_cvt_pk_fp8_f32(v.x * WSCALE, v.y * WSCALE, 0, false);
        p     = __builtin_amdgcn_cvt_pk_fp8_f32(v.z * WSCALE, v.w * WSCALE, p, true);
        Wq[j] = p;
    }
}

// ---------------- fused fp8 GEMM tile + online LSE partials ----------------
// R0 (verified 365us) base: 128x128 tile, 4 waves, ~3 blocks/CU.
// Change: B bypasses LDS entirely. Each lane loads its 32B of a W-row
// directly from global (16-lane group = 16 rows x 128B, fully coalesced),
// register double-buffered with a full-tile prefetch lead. LDS now holds
// only A (2 x 16KB dbuf) -> half the LDS reads, 34.8KB LDS keeps >=3
// blocks/CU of wave-overlap cover (the thing 256^2 variants lost).
__global__ __launch_bounds__(256, 3) void gemm_lse(
    const uint8_t* __restrict__ Xq,          // [BT,H] fp8
    const uint8_t* __restrict__ Wq,          // [V,H]  fp8 (pre-scaled x64)
    const float* __restrict__ bias,          // [V]
    const int*  __restrict__ target,         // [BT]
    float* __restrict__ part_m,              // [BT][PJ]
    float* __restrict__ part_l,              // [BT][PJ]
    float* __restrict__ tgt_logit)           // [BT]
{
    __shared__ __align__(16) uint8_t As[2][TM * BK];   // 32 KB, A double-buffer
    __shared__ float red_m[2][TM];
    __shared__ float red_l[2][TM];
    __shared__ int   tgts[TM];

    const int tid  = threadIdx.x;
    const int lane = tid & 63;
    const int wave = tid >> 6;       // 0..3
    const int wm   = wave >> 1;      // 64-row half
    const int wn   = wave & 1;       // 64-col half
    const int row0 = blockIdx.x * TM;
    const int col0 = blockIdx.y * TN;

    if (tid < TM) tgts[tid] = target[row0 + tid];

    f32x4 acc[4][4];
#pragma unroll
    for (int i = 0; i < 4; i++)
#pragma unroll
        for (int j = 0; j < 4; j++) acc[i][j] = (f32x4){0.f, 0.f, 0.f, 0.f};

    // A staging: lane l -> row 8g+l/8, physical chunk l%8 holds logical (l%8)^(l/8)
    const int srow   = lane >> 3;                    // 0..7
    const int schunk = ((lane & 7) ^ srow) * 16;     // pre-swizzled global byte off
    const uint8_t* Aptr = Xq + (size_t)(row0 + wave * 32 + srow) * H + schunk;

    const int lr  = lane & 15;
    const int g32 = lane >> 4;       // k-group: this lane's 32B chunk of each row

    // B: per-lane base for its 32B slice of row (col0 + wn*64 + lr); row j*16
    // offsets are compile-time (j*16*H) and fold into addressing.
    const uint8_t* Bbase = Wq + (size_t)(col0 + wn * 64 + lr) * H + g32 * 32;

    union Frag { int4 q[2]; v8i v; };

    auto stageA = [&](int buf) {
#pragma unroll
        for (int L = 0; L < 4; L++)
            async_load16(Aptr + (size_t)(8 * L) * H, &As[buf][(wave * 4 + L) * 1024]);
    };
    auto loadB = [&](Frag* b, int k) {
#pragma unroll
        for (int j = 0; j < 4; j++) {
            const uint8_t* bp = Bbase + (size_t)(j * 16) * H + k;
            b[j].q[0] = *(const int4*)(bp);
            b[j].q[1] = *(const int4*)(bp + 16);
        }
    };
    auto compute = [&](const uint8_t* As_, Frag* b) {
#pragma unroll
        for (int q = 0; q < 2; q++) {
            Frag a0, a1;
            {   // A-frag pair for rows 2q,2q+1 (16-row blocks)
                const int r0 = wm * 64 + (2 * q) * 16 + lr;
                const int p0 = (2 * g32) ^ (r0 & 7);
                const int4* base0 = (const int4*)&As_[r0 * BK];
                a0.q[0] = base0[p0];
                a0.q[1] = base0[p0 ^ 1];
                const int r1 = wm * 64 + (2 * q + 1) * 16 + lr;
                const int p1 = (2 * g32) ^ (r1 & 7);
                const int4* base1 = (const int4*)&As_[r1 * BK];
                a1.q[0] = base1[p1];
                a1.q[1] = base1[p1 ^ 1];
            }
            __builtin_amdgcn_s_setprio(1);
#pragma unroll
            for (int j = 0; j < 4; j++)
                acc[2 * q][j] = __builtin_amdgcn_mfma_scale_f32_16x16x128_f8f6f4(
                    a0.v, b[j].v, acc[2 * q][j],
                    0 /*A=e4m3*/, 0 /*B=e4m3*/,
                    0, 0x7f7f7f7f, 0, 0x7f7f7f7f);   // all scales = 2^0
#pragma unroll
            for (int j = 0; j < 4; j++)
                acc[2 * q + 1][j] = __builtin_amdgcn_mfma_scale_f32_16x16x128_f8f6f4(
                    a1.v, b[j].v, acc[2 * q + 1][j],
                    0, 0, 0, 0x7f7f7f7f, 0, 0x7f7f7f7f);
            __builtin_amdgcn_s_setprio(0);
        }
    };

    Frag bA[4], bB[4];

    // prologue: tile 0 -> As[0] + bA
    stageA(0); Aptr += BK;
    loadB(bA, 0);
    __syncthreads();                                 // vmcnt(0) drain + barrier

    for (int tt = 0; tt < NT; tt += 2) {
        // even tile tt: compute As[0]/bA; stage tile tt+1 (full-tile lead)
        stageA(1); Aptr += BK;
        loadB(bB, (tt + 1) * BK);
        compute(As[0], bA);
        __syncthreads();
        // odd tile tt+1: compute As[1]/bB; stage tile tt+2 if it exists
        if (tt + 2 < NT) {
            stageA(0); Aptr += BK;
            loadB(bA, (tt + 2) * BK);
        }
        compute(As[1], bB);
        __syncthreads();
    }

    // ---- epilogue (R0 verbatim): unscale, bias, target grab, reduce, exp pass
    const int quad = lane >> 4;
    float bj[4];
#pragma unroll
    for (int j = 0; j < 4; j++) bj[j] = bias[col0 + wn * 64 + j * 16 + lr];

#pragma unroll
    for (int i = 0; i < 4; i++) {
#pragma unroll
        for (int r = 0; r < 4; r++) {
            const int rit = wm * 64 + i * 16 + quad * 4 + r;  // C/D: row=quad*4+reg
            float v[4];
#pragma unroll
            for (int j = 0; j < 4; j++) v[j] = acc[i][j][r] * INV_WSCALE + bj[j];
            const int tg = tgts[rit];
#pragma unroll
            for (int j = 0; j < 4; j++)
                if (col0 + wn * 64 + j * 16 + lr == tg)
                    tgt_logit[row0 + rit] = v[j];  // exactly one writer globally
            float mx = fmaxf(fmaxf(v[0], v[1]), fmaxf(v[2], v[3]));
#pragma unroll
            for (int d = 1; d < 16; d <<= 1) mx = fmaxf(mx, __shfl_xor(mx, d));
            float se = __expf(v[0] - mx) + __expf(v[1] - mx) +
                       __expf(v[2] - mx) + __expf(v[3] - mx);
#pragma unroll
            for (int d = 1; d < 16; d <<= 1) se += __shfl_xor(se, d);
            if (lr == 0) { red_m[wn][rit] = mx; red_l[wn][rit] = se; }
        }
    }
    __syncthreads();
    if (tid < TM) {
        float m0 = red_m[0][tid], m1 = red_m[1][tid];
        float l0 = red_l[0][tid], l1 = red_l[1][tid];
        float M = fmaxf(m0, m1);
        float L = l0 * __expf(m0 - M) + l1 * __expf(m1 - M);
        part_m[(size_t)(row0 + tid) * PJ + blockIdx.y] = M;
        part_l[(size_t)(row0 + tid) * PJ + blockIdx.y] = L;
    }
}

// ------- merge partials: one WAVE per token, lane-parallel over V-tiles -----
__global__ void finalize(const float* __restrict__ part_m,
                         const float* __restrict__ part_l,
                         const float* __restrict__ tgt_logit,
                         const int*  __restrict__ target,
                         float* __restrict__ accum)  // accum[0]=sum, accum[1]=count
{
    const int wave = threadIdx.x >> 6, lane = threadIdx.x & 63;
    const int t = blockIdx.x * 4 + wave;             // grid = BT/4
    float m[4], l[4];
#pragma unroll
    for (int c = 0; c < 4; c++) {
        const int j = c * 64 + lane;
        const bool ok = j < NVT;
        m[c] = ok ? part_m[(size_t)t * PJ + j] : -1e30f;
        l[c] = ok ? part_l[(size_t)t * PJ + j] : 0.f;
    }
    float M = fmaxf(fmaxf(m[0], m[1]), fmaxf(m[2], m[3]));
#pragma unroll
    for (int d = 1; d < 64; d <<= 1) M = fmaxf(M, __shfl_xor(M, d));
    float S = l[0] * __expf(m[0] - M) + l[1] * __expf(m[1] - M) +
              l[2] * __expf(m[2] - M) + l[3] * __expf(m[3] - M);
#pragma unroll
    for (int d = 1; d < 64; d <<= 1) S += __shfl_xor(S, d);

    __shared__ float sm[4], sc[4];
    if (lane == 0) {
        const int tg = target[t];
        float loss = 0.f, cnt = 0.f;
        if (tg != -100) {
            loss = (M + __logf(S)) - tgt_logit[t];
            cnt  = 1.f;
        }
        sm[wave] = loss; sc[wave] = cnt;
    }
    __syncthreads();
    if (threadIdx.x == 0) {
        float Ls = sm[0] + sm[1] + sm[2] + sm[3];
        float Cs = sc[0] + sc[1] + sc[2] + sc[3];
        atomicAdd(&accum[0], Ls);
        atomicAdd(&accum[1], Cs);
    }
}

__global__ void final_div(const float* __restrict__ accum, float* __restrict__ out) {
    out[0] = accum[0] / fmaxf(accum[1], 1.f);
}

extern "C" void kernel_launch(void* const* d_in, const int* in_sizes, int n_in,
                              void* d_out, int out_size, void* d_ws, size_t ws_size,
                              hipStream_t stream) {
    const float* x      = (const float*)d_in[0];
    const int*   target = (const int*)d_in[1];
    const float* w      = (const float*)d_in[2];
    const float* bias   = (const float*)d_in[3];

    char* ws = (char*)d_ws;
    size_t off = 0;
    auto alloc = [&](size_t bytes) {
        void* p = ws + off;
        off += (bytes + 255) & ~(size_t)255;
        return p;
    };
    uint8_t* Xq   = (uint8_t*)alloc((size_t)BT * H);
    uint8_t* Wq   = (uint8_t*)alloc((size_t)V * H);
    float* part_m = (float*)alloc((size_t)BT * PJ * 4);
    float* part_l = (float*)alloc((size_t)BT * PJ * 4);
    float* tgtl   = (float*)alloc((size_t)BT * 4);
    float* accum  = (float*)alloc(256);

    const int nq = BT * H / 4 + (int)((size_t)V * H / 4);
    quant_all<<<(nq + 255) / 256, 256, 0, stream>>>(
        x, w, (int*)Xq, (int*)Wq, accum);

    dim3 grid(NRT, NVT);  // x fastest: consecutive blocks share the same W-tile
    gemm_lse<<<grid, 256, 0, stream>>>(Xq, Wq, bias, target, part_m, part_l, tgtl);

    finalize<<<BT / 4, 256, 0, stream>>>(part_m, part_l, tgtl, target, accum);

    final_div<<<1, 1, 0, stream>>>(accum, (float*)d_out);
}